// Round 5
// baseline (1970.401 us; speedup 1.0000x reference)
//
#include <hip/hip_runtime.h>

#define NU 100000
#define NM 50000

__device__ __forceinline__ float bcastf(float v, int lane) {
  return __int_as_float(__builtin_amdgcn_readlane(__float_as_int(v), lane));
}
__device__ __forceinline__ unsigned short f2bf(float f) {
  unsigned u = __float_as_uint(f);
  u = u + 0x7FFF + ((u >> 16) & 1);  // round-to-nearest-even
  return (unsigned short)(u >> 16);
}
__device__ __forceinline__ float bf2f(unsigned short b) {
  return __uint_as_float(((unsigned)b) << 16);
}

__global__ void k_count(const int* __restrict__ src, const int* __restrict__ dst,
                        int* cnt_u, int* cnt_m, int E) {
  int e = blockIdx.x * blockDim.x + threadIdx.x;
  if (e < E) {
    atomicAdd(&cnt_u[src[e]], 1);
    atomicAdd(&cnt_m[dst[e]], 1);
  }
}

__global__ void k_scan_part(const int* __restrict__ cnt, int* __restrict__ off,
                            int* __restrict__ bsum, int n) {
  __shared__ int wsum[4];
  int t = threadIdx.x;
  int base = blockIdx.x * 1024 + t * 4;
  int v0 = (base + 0 < n) ? cnt[base + 0] : 0;
  int v1 = (base + 1 < n) ? cnt[base + 1] : 0;
  int v2 = (base + 2 < n) ? cnt[base + 2] : 0;
  int v3 = (base + 3 < n) ? cnt[base + 3] : 0;
  int s = v0 + v1 + v2 + v3;
  int lane = t & 63;
  int inc = s;
  #pragma unroll
  for (int d = 1; d < 64; d <<= 1) {
    int x = __shfl_up(inc, d);
    if (lane >= d) inc += x;
  }
  int wid = t >> 6;
  if (lane == 63) wsum[wid] = inc;
  __syncthreads();
  int woff = 0;
  for (int i = 0; i < wid; i++) woff += wsum[i];
  int excl = woff + inc - s;
  if (base + 0 < n) off[base + 0] = excl;
  if (base + 1 < n) off[base + 1] = excl + v0;
  if (base + 2 < n) off[base + 2] = excl + v0 + v1;
  if (base + 3 < n) off[base + 3] = excl + v0 + v1 + v2;
  if (t == 255) bsum[blockIdx.x] = woff + inc;
}

__global__ void k_scan_top(int* bsum, int nb) {
  int lane = threadIdx.x;  // block of 64
  int carry = 0;
  for (int base = 0; base < nb; base += 64) {
    int i = base + lane;
    int v = (i < nb) ? bsum[i] : 0;
    int inc = v;
    #pragma unroll
    for (int d = 1; d < 64; d <<= 1) {
      int x = __shfl_up(inc, d);
      if (lane >= d) inc += x;
    }
    if (i < nb) bsum[i] = carry + inc - v;
    carry += __shfl(inc, 63);
  }
}

__global__ void k_scan_add(int* __restrict__ off, int* __restrict__ cur,
                           const int* __restrict__ bsum, int n, int total) {
  int i = blockIdx.x * blockDim.x + threadIdx.x;
  if (i < n) {
    int v = off[i] + bsum[i >> 10];
    off[i] = v;
    cur[i] = v;
  } else if (i == n) {
    off[n] = total;
  }
}

__global__ void k_scatter(const int* __restrict__ src, const int* __restrict__ dst,
                          int* cur_u, int* cur_m,
                          int* __restrict__ nbr_u, int* __restrict__ nbr_m, int E) {
  int e = blockIdx.x * blockDim.x + threadIdx.x;
  if (e < E) {
    int s = src[e], d = dst[e];
    int pu = atomicAdd(&cur_u[s], 1);
    nbr_u[pu] = d;
    int pm = atomicAdd(&cur_m[d], 1);
    nbr_m[pm] = s;
  }
}

// f32 -> bf16 table conversion, 4 elems/thread
__global__ void k_tobf4(const float4* __restrict__ in, unsigned short* __restrict__ out, int n4) {
  int i = blockIdx.x * blockDim.x + threadIdx.x;
  if (i < n4) {
    float4 v = in[i];
    ushort4 o;
    o.x = f2bf(v.x); o.y = f2bf(v.y); o.z = f2bf(v.z); o.w = f2bf(v.w);
    *(ushort4*)(out + (size_t)i * 4) = o;
  }
}

// x_movie(bf16) = movie_x @ lin_W.T + lin_b + movie_emb  (wave per movie, lane = h)
__global__ void k_movie_init(const float* __restrict__ movie_x,
                             const float* __restrict__ lin_W,
                             const float* __restrict__ lin_b,
                             const float* __restrict__ movie_emb,
                             unsigned short* __restrict__ x_movie) {
  int w = (blockIdx.x * blockDim.x + threadIdx.x) >> 6;
  int h = threadIdx.x & 63;
  if (w >= NM) return;
  float acc = lin_b[h] + movie_emb[(size_t)w * 64 + h];
  const float* mx = movie_x + (size_t)w * 20;
  const float* lw = lin_W + (size_t)h * 20;
  #pragma unroll
  for (int f = 0; f < 20; f++) acc += mx[f] * lw[f];
  x_movie[(size_t)w * 64 + h] = f2bf(acc);
}

// One wave per destination node; movie dests then user dests in one grid.
// PACKED GATHER: lane l = (row-slot g=l>>3, 16B-chunk i=l&7). One dwordx4
// instruction gathers 8 neighbor rows (8 lanes x 16B = one 128B bf16 row
// each) -> 8x fewer gather instructions than one-row-per-instruction.
// Neighbor ids fetched coalesced per 64-window, redistributed per chunk
// with one ds_bpermute. Tail: clamped index + 0/1 float mask folded into
// fmac. Per-node cross-group reduce via shfl_xor {8,16,32}.
template <int RELU, int OUT_BF>
__global__ void __launch_bounds__(256)
k_agg_dual(const unsigned short* __restrict__ xu, const unsigned short* __restrict__ xm,
           const int* __restrict__ nbrM, const int* __restrict__ offM,
           const float* __restrict__ WlM, const float* __restrict__ WrM,
           const float* __restrict__ bM, void* __restrict__ outM,
           const int* __restrict__ nbrU, const int* __restrict__ offU,
           const float* __restrict__ WlU, const float* __restrict__ WrU,
           const float* __restrict__ bU, void* __restrict__ outU) {
  int gw = (blockIdx.x * blockDim.x + threadIdx.x) >> 6;
  int lane = threadIdx.x & 63;
  if (gw >= NM + NU) return;  // wave-uniform
  const unsigned short* xsrc;
  const unsigned short* xdst;
  const int* nbr;
  const int* off;
  const float* Wl;
  const float* Wr;
  const float* bias;
  void* out;
  int w;
  if (gw < NM) {
    w = gw; xsrc = xu; xdst = xm; nbr = nbrM; off = offM;
    Wl = WlM; Wr = WrM; bias = bM; out = outM;
  } else {
    w = gw - NM; xsrc = xm; xdst = xu; nbr = nbrU; off = offU;
    Wl = WlU; Wr = WrU; bias = bU; out = outU;
  }
  int g = lane >> 3;   // row slot within chunk
  int i = lane & 7;    // 16B sub-offset within row
  int s = off[w], e = off[w + 1];
  float aa[8];
  #pragma unroll
  for (int k = 0; k < 8; k++) aa[k] = 0.f;

  for (int base = s; base < e; base += 64) {
    int cnw = e - base;
    if (cnw > 64) cnw = 64;
    int lim = cnw - 1;
    int my = nbr[base + (lane < cnw ? lane : 0)];  // coalesced window load
    // chunks 0..3 always; 4..7 under uniform branch (avg user deg ~25)
    uint4 d0, d1, d2, d3, d4, d5, d6, d7;
    int j0 = __shfl(my, min(0 * 8 + g, lim));
    int j1 = __shfl(my, min(1 * 8 + g, lim));
    int j2 = __shfl(my, min(2 * 8 + g, lim));
    int j3 = __shfl(my, min(3 * 8 + g, lim));
    d0 = *(const uint4*)(xsrc + (size_t)j0 * 64 + i * 8);
    d1 = *(const uint4*)(xsrc + (size_t)j1 * 64 + i * 8);
    d2 = *(const uint4*)(xsrc + (size_t)j2 * 64 + i * 8);
    d3 = *(const uint4*)(xsrc + (size_t)j3 * 64 + i * 8);
    bool hi = cnw > 32;
    if (hi) {
      int j4 = __shfl(my, min(4 * 8 + g, lim));
      int j5 = __shfl(my, min(5 * 8 + g, lim));
      int j6 = __shfl(my, min(6 * 8 + g, lim));
      int j7 = __shfl(my, min(7 * 8 + g, lim));
      d4 = *(const uint4*)(xsrc + (size_t)j4 * 64 + i * 8);
      d5 = *(const uint4*)(xsrc + (size_t)j5 * 64 + i * 8);
      d6 = *(const uint4*)(xsrc + (size_t)j6 * 64 + i * 8);
      d7 = *(const uint4*)(xsrc + (size_t)j7 * 64 + i * 8);
    }
    #define CONSUME(dd, c)                                              \
      {                                                                 \
        float mc = ((c) * 8 + g < cnw) ? 1.f : 0.f;                     \
        aa[0] = fmaf(__uint_as_float(dd.x << 16), mc, aa[0]);           \
        aa[1] = fmaf(__uint_as_float(dd.x & 0xFFFF0000u), mc, aa[1]);   \
        aa[2] = fmaf(__uint_as_float(dd.y << 16), mc, aa[2]);           \
        aa[3] = fmaf(__uint_as_float(dd.y & 0xFFFF0000u), mc, aa[3]);   \
        aa[4] = fmaf(__uint_as_float(dd.z << 16), mc, aa[4]);           \
        aa[5] = fmaf(__uint_as_float(dd.z & 0xFFFF0000u), mc, aa[5]);   \
        aa[6] = fmaf(__uint_as_float(dd.w << 16), mc, aa[6]);           \
        aa[7] = fmaf(__uint_as_float(dd.w & 0xFFFF0000u), mc, aa[7]);   \
      }
    CONSUME(d0, 0)
    CONSUME(d1, 1)
    CONSUME(d2, 2)
    CONSUME(d3, 3)
    if (hi) {
      CONSUME(d4, 4)
      CONSUME(d5, 5)
      CONSUME(d6, 6)
      CONSUME(d7, 7)
    }
    #undef CONSUME
  }
  // cross-row-slot reduce: sum over g (lane bits 3..5)
  #pragma unroll
  for (int m = 8; m <= 32; m <<= 1) {
    #pragma unroll
    for (int k = 0; k < 8; k++) aa[k] += __shfl_xor(aa[k], m);
  }
  // now every lane holds totals for features f = 8*(lane&7)+k in aa[k]
  float inv = 1.0f / fmaxf((float)(e - s), 1.0f);
  #pragma unroll
  for (int k = 0; k < 8; k++) aa[k] *= inv;  // mean
  float dv = bf2f(xdst[(size_t)w * 64 + lane]);

  // transform: out[h] = sum_k mean[k]*Wl[h][k] + dv[k]*Wr[h][k] + b[h]
  // mean[kk] = readlane(aa[kk&7], kk>>3) (compile-time lanes);
  // weights register-blocked (float4) to keep VGPR low.
  float acc = bias[lane];
  const float4* wl4 = (const float4*)(Wl + (size_t)lane * 64);
  const float4* wr4 = (const float4*)(Wr + (size_t)lane * 64);
  #pragma unroll
  for (int blk = 0; blk < 16; blk++) {
    float4 a4 = wl4[blk];
    float4 c4 = wr4[blk];
    acc += bcastf(aa[(4 * blk + 0) & 7], (4 * blk + 0) >> 3) * a4.x;
    acc += bcastf(aa[(4 * blk + 1) & 7], (4 * blk + 1) >> 3) * a4.y;
    acc += bcastf(aa[(4 * blk + 2) & 7], (4 * blk + 2) >> 3) * a4.z;
    acc += bcastf(aa[(4 * blk + 3) & 7], (4 * blk + 3) >> 3) * a4.w;
    acc += bcastf(dv, 4 * blk + 0) * c4.x;
    acc += bcastf(dv, 4 * blk + 1) * c4.y;
    acc += bcastf(dv, 4 * blk + 2) * c4.z;
    acc += bcastf(dv, 4 * blk + 3) * c4.w;
  }
  if (RELU) acc = fmaxf(acc, 0.0f);
  if (OUT_BF)
    ((unsigned short*)out)[(size_t)w * 64 + lane] = f2bf(acc);
  else
    ((float*)out)[(size_t)w * 64 + lane] = acc;
}

// 16 lanes per edge: float4 row reads (256B contiguous), shfl_xor reduce,
// 4 consecutive stores per wave. 16 edges per 256-thread block.
__global__ void __launch_bounds__(256)
k_dot(const float* __restrict__ u2, const float* __restrict__ m2,
      const int* __restrict__ eu, const int* __restrict__ em,
      float* __restrict__ out, int L) {
  int wave = (blockIdx.x * blockDim.x + threadIdx.x) >> 6;
  int lane = threadIdx.x & 63;
  int sub = lane & 15;
  int l = wave * 4 + (lane >> 4);
  int lc = l < L ? l : (L - 1);
  int iu = eu[lc], im = em[lc];
  float4 x = ((const float4*)(u2 + (size_t)iu * 64))[sub];
  float4 y = ((const float4*)(m2 + (size_t)im * 64))[sub];
  float s = x.x * y.x + x.y * y.y + x.z * y.z + x.w * y.w;
  s += __shfl_xor(s, 1);
  s += __shfl_xor(s, 2);
  s += __shfl_xor(s, 4);
  s += __shfl_xor(s, 8);
  if (sub == 0 && l < L) out[l] = s;
}

extern "C" void kernel_launch(void* const* d_in, const int* in_sizes, int n_in,
                              void* d_out, int out_size, void* d_ws, size_t ws_size,
                              hipStream_t stream) {
  const float* movie_x   = (const float*)d_in[2];
  const int*   esrc      = (const int*)d_in[3];
  const int*   edst      = (const int*)d_in[4];
  const int*   eli_u     = (const int*)d_in[5];
  const int*   eli_m     = (const int*)d_in[6];
  const float* user_emb  = (const float*)d_in[7];
  const float* movie_emb = (const float*)d_in[8];
  const float* lin_W     = (const float*)d_in[9];
  const float* lin_b     = (const float*)d_in[10];
  const float* W1um_l = (const float*)d_in[11];
  const float* W1um_r = (const float*)d_in[12];
  const float* W1mu_l = (const float*)d_in[13];
  const float* W1mu_r = (const float*)d_in[14];
  const float* W2um_l = (const float*)d_in[15];
  const float* W2um_r = (const float*)d_in[16];
  const float* W2mu_l = (const float*)d_in[17];
  const float* W2mu_r = (const float*)d_in[18];
  const float* b1um = (const float*)d_in[19];
  const float* b1mu = (const float*)d_in[20];
  const float* b2um = (const float*)d_in[21];
  const float* b2mu = (const float*)d_in[22];
  const int E = in_sizes[3];
  const int L = in_sizes[5];

  char* ws = (char*)d_ws;
  size_t o = 0;
  auto alloc = [&](size_t bytes) -> void* {
    void* p = ws + o;
    o = (o + bytes + 255) & ~(size_t)255;
    return p;
  };
  unsigned short* uemb_bf   = (unsigned short*)alloc((size_t)NU * 64 * 2);
  unsigned short* xmovie_bf = (unsigned short*)alloc((size_t)NM * 64 * 2);
  unsigned short* m1_bf     = (unsigned short*)alloc((size_t)NM * 64 * 2);
  unsigned short* u1_bf     = (unsigned short*)alloc((size_t)NU * 64 * 2);
  float* m2 = (float*)alloc((size_t)NM * 64 * 4);
  float* u2 = (float*)alloc((size_t)NU * 64 * 4);
  int* cnt_m = (int*)alloc((size_t)NM * 4);
  int* cnt_u = (int*)alloc((size_t)NU * 4);
  int* off_m = (int*)alloc((size_t)(NM + 1) * 4);
  int* off_u = (int*)alloc((size_t)(NU + 1) * 4);
  int* cur_m = (int*)alloc((size_t)NM * 4);
  int* cur_u = (int*)alloc((size_t)NU * 4);
  int* bs_m  = (int*)alloc(4096);
  int* bs_u  = (int*)alloc(4096);
  int* nbr_m = (int*)alloc((size_t)E * 4);
  int* nbr_u = (int*)alloc((size_t)E * 4);

  hipMemsetAsync(cnt_m, 0, (size_t)NM * 4, stream);
  hipMemsetAsync(cnt_u, 0, (size_t)NU * 4, stream);

  int gE = (E + 255) / 256;
  k_count<<<gE, 256, 0, stream>>>(esrc, edst, cnt_u, cnt_m, E);

  int nbm = (NM + 1023) / 1024, nbu = (NU + 1023) / 1024;
  k_scan_part<<<nbm, 256, 0, stream>>>(cnt_m, off_m, bs_m, NM);
  k_scan_part<<<nbu, 256, 0, stream>>>(cnt_u, off_u, bs_u, NU);
  k_scan_top<<<1, 64, 0, stream>>>(bs_m, nbm);
  k_scan_top<<<1, 64, 0, stream>>>(bs_u, nbu);
  k_scan_add<<<(NM + 1 + 255) / 256, 256, 0, stream>>>(off_m, cur_m, bs_m, NM, E);
  k_scan_add<<<(NU + 1 + 255) / 256, 256, 0, stream>>>(off_u, cur_u, bs_u, NU, E);
  k_scatter<<<gE, 256, 0, stream>>>(esrc, edst, cur_u, cur_m, nbr_u, nbr_m, E);

  // bf16 gather tables
  int n4u = NU * 16;  // NU*64/4
  k_tobf4<<<(n4u + 255) / 256, 256, 0, stream>>>((const float4*)user_emb, uemb_bf, n4u);
  k_movie_init<<<(NM + 3) / 4, 256, 0, stream>>>(movie_x, lin_W, lin_b, movie_emb, xmovie_bf);

  int gAgg = (NM + NU + 3) / 4;
  // layer 1 (ReLU), bf16 outputs (they are layer-2 gather tables)
  k_agg_dual<1, 1><<<gAgg, 256, 0, stream>>>(uemb_bf, xmovie_bf,
                                             nbr_m, off_m, W1um_l, W1um_r, b1um, m1_bf,
                                             nbr_u, off_u, W1mu_l, W1mu_r, b1mu, u1_bf);
  // layer 2 (no activation), f32 outputs for the dot
  k_agg_dual<0, 0><<<gAgg, 256, 0, stream>>>(u1_bf, m1_bf,
                                             nbr_m, off_m, W2um_l, W2um_r, b2um, m2,
                                             nbr_u, off_u, W2mu_l, W2mu_r, b2mu, u2);

  // 16 edges per 256-thread block
  k_dot<<<(L + 15) / 16, 256, 0, stream>>>(u2, m2, eli_u, eli_m, (float*)d_out, L);
}